// Round 1
// baseline (5024.663 us; speedup 1.0000x reference)
//
#include <hip/hip_runtime.h>

#define NHEAD 8
#define HDIM 32
#define CCH 256
#define HH 256
#define WWIDTH 256
#define SHIFT_ 4
#define P2 64

// One block per (batch, window): grid = 4*1024, block = 256 threads.
__global__ __launch_bounds__(256) void swin_fused(
    const float* __restrict__ x, const float* __restrict__ Wqkv,
    const float* __restrict__ bqkv, const float* __restrict__ relp,
    const float* __restrict__ Wout, const float* __restrict__ bout,
    float* __restrict__ out)
{
  __shared__ float xs[P2 * CCH];   // 64KB: x window, fp32
  __shared__ float qs[P2 * 36];    // q (later: per-head attn out), padded stride 36
  __shared__ float ks_[P2 * 36];
  __shared__ float vs[P2 * 36];
  __shared__ float ss[P2 * 68];    // sim/probs, padded stride 68 (16B aligned rows)
  __shared__ float red[128];       // row max / inv-sum

  const int tx = threadIdx.x;
  const int bw = blockIdx.x;
  const int b  = bw >> 10;
  const int w  = bw & 1023;
  const int wh = w >> 5, wwi = w & 31;

  const int c32 = tx & 31, r8 = tx >> 5;

  // ---- load x window (roll by -4 == read from (r+4)&255) ----
  {
    const int ch = (tx & 63) * 4;
    const int pt = tx >> 6;
    for (int pc = 0; pc < 16; ++pc) {
      const int p  = pc * 4 + pt;
      const int pi = p >> 3, pj = p & 7;
      const int sr = (wh * 8 + pi + SHIFT_) & 255;
      const int sc = (wwi * 8 + pj + SHIFT_) & 255;
      const float4 v4 = *reinterpret_cast<const float4*>(
          x + (size_t)((b * HH + sr) * WWIDTH + sc) * CCH + ch);
      *reinterpret_cast<float4*>(xs + p * CCH + ch) = v4;
    }
  }

  float acc[8][8];
  #pragma unroll
  for (int i = 0; i < 8; ++i)
    #pragma unroll
    for (int j = 0; j < 8; ++j) acc[i][j] = 0.f;

  __syncthreads();

  const bool mrow = (wh == 31), mcol = (wwi == 31);

  for (int h = 0; h < NHEAD; ++h) {
    // ---- QKV projection for head h: out 64 x (32q + 32k + 32v) ----
    {
      const int colq = h * 32 + c32;
      float accq[8], acck[8], accv[8];
      const float bq = bqkv[colq], bk = bqkv[256 + colq], bv = bqkv[512 + colq];
      #pragma unroll
      for (int pb = 0; pb < 8; ++pb) { accq[pb] = bq; acck[pb] = bk; accv[pb] = bv; }
      for (int k4 = 0; k4 < 64; ++k4) {
        float4 xv[8];
        #pragma unroll
        for (int pb = 0; pb < 8; ++pb)
          xv[pb] = *reinterpret_cast<const float4*>(xs + (r8 + 8 * pb) * CCH + k4 * 4);
        #pragma unroll
        for (int kk = 0; kk < 4; ++kk) {
          const int k = k4 * 4 + kk;
          const float wq = Wqkv[k * 768 + colq];
          const float wk = Wqkv[k * 768 + 256 + colq];
          const float wv = Wqkv[k * 768 + 512 + colq];
          #pragma unroll
          for (int pb = 0; pb < 8; ++pb) {
            const float xk = (kk == 0) ? xv[pb].x : (kk == 1) ? xv[pb].y
                           : (kk == 2) ? xv[pb].z : xv[pb].w;
            accq[pb] = fmaf(xk, wq, accq[pb]);
            acck[pb] = fmaf(xk, wk, acck[pb]);
            accv[pb] = fmaf(xk, wv, accv[pb]);
          }
        }
      }
      #pragma unroll
      for (int pb = 0; pb < 8; ++pb) {
        const int p = r8 + 8 * pb;
        qs[p * 36 + c32]  = accq[pb];
        ks_[p * 36 + c32] = acck[pb];
        vs[p * 36 + c32]  = accv[pb];
      }
    }
    __syncthreads();

    // ---- sim = q.k^T * scale + rel_pos, with shift mask ----
    {
      const int p  = tx >> 2;
      const int q0 = (tx & 3) * 16;
      const int pi = p >> 3, pj = p & 7;
      float qr[32];
      #pragma unroll
      for (int dd = 0; dd < 32; ++dd) qr[dd] = qs[p * 36 + dd];
      for (int qq = q0; qq < q0 + 16; ++qq) {
        const int qi = qq >> 3, qj = qq & 7;
        float d = 0.f;
        #pragma unroll
        for (int d4 = 0; d4 < 8; ++d4) {
          const float4 kv = *reinterpret_cast<const float4*>(ks_ + qq * 36 + d4 * 4);
          d = fmaf(qr[d4 * 4 + 0], kv.x, d);
          d = fmaf(qr[d4 * 4 + 1], kv.y, d);
          d = fmaf(qr[d4 * 4 + 2], kv.z, d);
          d = fmaf(qr[d4 * 4 + 3], kv.w, d);
        }
        d = d * 0.17677669529663687f
            + relp[h * 225 + (pi - qi + 7) * 15 + (pj - qj + 7)];
        const bool masked = (mrow && ((pi < 4) != (qi < 4)))
                         || (mcol && ((pj < 4) != (qj < 4)));
        ss[p * 68 + qq] = masked ? -1e30f : d;
      }
    }
    __syncthreads();

    // ---- softmax stats (one thread per row) ----
    if (tx < 64) {
      float m = -1e30f;
      for (int qq = 0; qq < 64; ++qq) m = fmaxf(m, ss[tx * 68 + qq]);
      float s = 0.f;
      for (int qq = 0; qq < 64; ++qq) s += __expf(ss[tx * 68 + qq] - m);
      red[tx] = m;
      red[64 + tx] = 1.f / s;
    }
    __syncthreads();

    // ---- probs in-place ----
    {
      const int p  = tx >> 2;
      const int q0 = (tx & 3) * 16;
      const float m = red[p], rinv = red[64 + p];
      for (int qq = q0; qq < q0 + 16; ++qq)
        ss[p * 68 + qq] = __expf(ss[p * 68 + qq] - m) * rinv;
    }
    __syncthreads();

    // ---- PV: attn[p][d] = sum_q probs[p][q] * v[q][d]  (into qs) ----
    {
      float av[8];
      #pragma unroll
      for (int pb = 0; pb < 8; ++pb) av[pb] = 0.f;
      for (int q4 = 0; q4 < 16; ++q4) {
        float vv[4];
        #pragma unroll
        for (int kk = 0; kk < 4; ++kk) vv[kk] = vs[(q4 * 4 + kk) * 36 + c32];
        #pragma unroll
        for (int pb = 0; pb < 8; ++pb) {
          const float4 pr = *reinterpret_cast<const float4*>(ss + (r8 + 8 * pb) * 68 + q4 * 4);
          av[pb] = fmaf(pr.x, vv[0], av[pb]);
          av[pb] = fmaf(pr.y, vv[1], av[pb]);
          av[pb] = fmaf(pr.z, vv[2], av[pb]);
          av[pb] = fmaf(pr.w, vv[3], av[pb]);
        }
      }
      #pragma unroll
      for (int pb = 0; pb < 8; ++pb)
        qs[(r8 + 8 * pb) * 36 + c32] = av[pb];
    }
    __syncthreads();

    // ---- out-proj partial: acc += attn_h @ Wout[h*32:(h+1)*32, :] ----
    {
      for (int d4 = 0; d4 < 8; ++d4) {
        float4 at[8];
        #pragma unroll
        for (int pl = 0; pl < 8; ++pl)
          at[pl] = *reinterpret_cast<const float4*>(qs + (r8 * 8 + pl) * 36 + d4 * 4);
        #pragma unroll
        for (int kk = 0; kk < 4; ++kk) {
          const float* wrow = Wout + (h * 32 + d4 * 4 + kk) * 256 + c32;
          #pragma unroll
          for (int g = 0; g < 8; ++g) {
            const float wv = wrow[g * 32];
            #pragma unroll
            for (int pl = 0; pl < 8; ++pl) {
              const float av = (kk == 0) ? at[pl].x : (kk == 1) ? at[pl].y
                             : (kk == 2) ? at[pl].z : at[pl].w;
              acc[pl][g] = fmaf(av, wv, acc[pl][g]);
            }
          }
        }
      }
    }
    __syncthreads();
  }

  // ---- write out (+bias), roll back by +4 == write to (r+4)&255 ----
  #pragma unroll
  for (int pl = 0; pl < 8; ++pl) {
    const int p  = r8 * 8 + pl;
    const int pi = p >> 3, pj = p & 7;
    const int dr = (wh * 8 + pi + SHIFT_) & 255;
    const int dc = (wwi * 8 + pj + SHIFT_) & 255;
    float* orow = out + (size_t)((b * HH + dr) * WWIDTH + dc) * CCH;
    #pragma unroll
    for (int g = 0; g < 8; ++g) {
      const int j = g * 32 + c32;
      orow[j] = acc[pl][g] + bout[j];
    }
  }
}

extern "C" void kernel_launch(void* const* d_in, const int* in_sizes, int n_in,
                              void* d_out, int out_size, void* d_ws, size_t ws_size,
                              hipStream_t stream) {
  (void)in_sizes; (void)n_in; (void)out_size; (void)d_ws; (void)ws_size;
  const float* x    = (const float*)d_in[0];
  const float* Wqkv = (const float*)d_in[1];
  const float* bqkv = (const float*)d_in[2];
  const float* relp = (const float*)d_in[3];
  const float* Wout = (const float*)d_in[4];
  const float* bout = (const float*)d_in[5];
  float* out = (float*)d_out;

  dim3 grid(4 * 1024), block(256);
  hipLaunchKernelGGL(swin_fused, grid, block, 0, stream,
                     x, Wqkv, bqkv, relp, Wout, bout, out);
}

// Round 4
// 641.242 us; speedup vs baseline: 7.8358x; 7.8358x over previous
//
#include <hip/hip_runtime.h>

typedef __attribute__((ext_vector_type(4))) float f32x4;
typedef __attribute__((ext_vector_type(8))) short s16x8;
typedef __attribute__((ext_vector_type(4))) short s16x4;
typedef __attribute__((ext_vector_type(8))) __bf16 bf16v8;

// LDS layout (bytes)
#define LDS_XS 0        // 32768: x window bf16 [64][256] swz512; phase2: attn_lo
#define LDS_QS 32768    // 32768: Q bf16 [64][256] (pre-scaled) swz512; phase2: attn_hi
#define LDS_KS 65536    // 32768: K bf16 [64][256], swz512
#define LDS_VT 98304    // 32768: V^T bf16 [256][64], swz128
#define LDS_PR 131072   // 16384: probs bf16 [2][64][64], swz128
#define LDS_RP 147456   // 7200:  rel_pos f32 [8*225]
#define LDS_TOT 154656

__device__ __forceinline__ f32x4 mfma16(s16x8 a, s16x8 b, f32x4 c) {
  return __builtin_amdgcn_mfma_f32_16x16x32_bf16(
      __builtin_bit_cast(bf16v8, a), __builtin_bit_cast(bf16v8, b), c, 0, 0, 0);
}

__device__ __forceinline__ short f2bf(float f) {
  unsigned u = __float_as_uint(f);
  u += 0x7fffu + ((u >> 16) & 1u);
  return (short)(u >> 16);
}
__device__ __forceinline__ float bf2f(short h) {
  return __uint_as_float(((unsigned)(unsigned short)h) << 16);
}

__device__ __forceinline__ int swz512(int row, int colByte) {
  return row * 512 + (colByte ^ ((row & 7) << 4));
}
__device__ __forceinline__ int swz128(int row, int colByte) {
  return row * 128 + (colByte ^ ((row & 7) << 4));
}

// Prep: WqkvT[n][k] (768x256) bf16; WoutT hi/lo [n][k] (256x256) bf16 split.
__global__ void prep_w(const float* __restrict__ Wqkv, const float* __restrict__ Wout,
                       short* __restrict__ wqkvT, short* __restrict__ woutTh,
                       short* __restrict__ woutTl) {
  int t = blockIdx.x * 256 + threadIdx.x;
  if (t < 768 * 256) {
    int n = t >> 8, k = t & 255;
    wqkvT[t] = f2bf(Wqkv[k * 768 + n]);
  } else {
    int t2 = t - 768 * 256;
    int n = t2 >> 8, k = t2 & 255;
    float wv = Wout[k * 256 + n];
    short hi = f2bf(wv);
    woutTh[t2] = hi;
    woutTl[t2] = f2bf(wv - bf2f(hi));
  }
}

// One block per (batch, window). 512 threads = 8 waves.
__global__ __launch_bounds__(512, 2) void swin_mfma(
    const float* __restrict__ x, const float* __restrict__ bqkv,
    const float* __restrict__ relp, const float* __restrict__ bout,
    const short* __restrict__ wqkvT, const short* __restrict__ woutTh,
    const short* __restrict__ woutTl, float* __restrict__ out)
{
  __shared__ __align__(16) char lds[LDS_TOT];

  const int tx = threadIdx.x;
  const int w  = tx >> 6;         // wave 0..7
  const int l  = tx & 63;         // lane
  const int g  = l >> 4;          // k-group 0..3
  const int li = l & 15;          // row/col within fragment

  const int b   = blockIdx.x >> 10;
  const int wdw = blockIdx.x & 1023;
  const int wh  = wdw >> 5, wwi = wdw & 31;

  // ---- Phase 0: stage x window (rolled -4) as bf16 into LDS; rel_pos to LDS ----
  for (int i = 0; i < 8; ++i) {
    int idx = tx + i * 512;       // 0..4095
    int p = idx >> 6, c4 = idx & 63;
    int pi = p >> 3, pj = p & 7;
    int sr = (wh * 8 + pi + 4) & 255;
    int sc = (wwi * 8 + pj + 4) & 255;
    f32x4 v = *(const f32x4*)(x + ((((size_t)b * 256 + sr) * 256 + sc) * 256 + c4 * 4));
    s16x4 h4;
    h4.x = f2bf(v.x); h4.y = f2bf(v.y); h4.z = f2bf(v.z); h4.w = f2bf(v.w);
    *(s16x4*)(lds + LDS_XS + swz512(p, c4 * 8)) = h4;
  }
  for (int i = tx; i < 1800; i += 512)
    ((float*)(lds + LDS_RP))[i] = relp[i];
  __syncthreads();

  // ---- Phase 1: QKV GEMM. 48 col-blocks of 16 (Q:0-15, K:16-31, V:32-47); wave w owns 6. ----
  {
    f32x4 acc[6][4];
    #pragma unroll
    for (int j = 0; j < 6; ++j)
      #pragma unroll
      for (int rb = 0; rb < 4; ++rb)
        acc[j][rb] = (f32x4){0.f, 0.f, 0.f, 0.f};

    s16x8 bcur[6], bnext[6];
    #pragma unroll
    for (int j = 0; j < 6; ++j)
      bcur[j] = *(const s16x8*)(wqkvT + (size_t)((w * 6 + j) * 16 + li) * 256 + g * 8);

    #pragma unroll
    for (int kk = 0; kk < 8; ++kk) {
      s16x8 a[4];
      #pragma unroll
      for (int rb = 0; rb < 4; ++rb)
        a[rb] = *(const s16x8*)(lds + LDS_XS + swz512(rb * 16 + li, (kk * 32 + g * 8) * 2));
      if (kk < 7) {
        #pragma unroll
        for (int j = 0; j < 6; ++j)
          bnext[j] = *(const s16x8*)(wqkvT + (size_t)((w * 6 + j) * 16 + li) * 256
                                      + (kk + 1) * 32 + g * 8);
      }
      #pragma unroll
      for (int j = 0; j < 6; ++j)
        #pragma unroll
        for (int rb = 0; rb < 4; ++rb)
          acc[j][rb] = mfma16(a[rb], bcur[j], acc[j][rb]);
      if (kk < 7) {
        #pragma unroll
        for (int j = 0; j < 6; ++j) bcur[j] = bnext[j];
      }
    }

    // stores: Q row-major (pre-scaled), K row-major, V transposed
    #pragma unroll
    for (int j = 0; j < 6; ++j) {
      const int cb = w * 6 + j;
      if (cb < 16) {            // Q
        const float bq = bqkv[cb * 16 + li];
        #pragma unroll
        for (int rb = 0; rb < 4; ++rb)
          #pragma unroll
          for (int r = 0; r < 4; ++r) {
            int m = rb * 16 + g * 4 + r;
            *(short*)(lds + LDS_QS + swz512(m, (cb * 16 + li) * 2)) =
                f2bf((acc[j][rb][r] + bq) * 0.17677669529663687f);
          }
      } else if (cb < 32) {     // K
        const float bk = bqkv[256 + (cb - 16) * 16 + li];
        #pragma unroll
        for (int rb = 0; rb < 4; ++rb)
          #pragma unroll
          for (int r = 0; r < 4; ++r) {
            int m = rb * 16 + g * 4 + r;
            *(short*)(lds + LDS_KS + swz512(m, ((cb - 16) * 16 + li) * 2)) =
                f2bf(acc[j][rb][r] + bk);
          }
      } else {                  // V -> vT[d][p]
        const float bv = bqkv[512 + (cb - 32) * 16 + li];
        const int d = (cb - 32) * 16 + li;
        #pragma unroll
        for (int rb = 0; rb < 4; ++rb) {
          s16x4 pk;
          pk.x = f2bf(acc[j][rb][0] + bv);
          pk.y = f2bf(acc[j][rb][1] + bv);
          pk.z = f2bf(acc[j][rb][2] + bv);
          pk.w = f2bf(acc[j][rb][3] + bv);
          *(s16x4*)(lds + LDS_VT + swz128(d, (rb * 16 + g * 4) * 2)) = pk;
        }
      }
    }
  }
  __syncthreads();

  // ---- Phase 2: attention. Wave w: head = hp*2 + (w>>2), rows (w&3)*16..+15. No barriers. ----
  {
    const bool mrow = (wh == 31), mcol = (wwi == 31);
    const int hsel = w >> 2, strip = w & 3, p0 = strip * 16;

    #pragma unroll
    for (int hp = 0; hp < 4; ++hp) {
      const int h = hp * 2 + hsel;

      // sim = Q.K^T (Q pre-scaled): 4 col-tiles, K=32 in one MFMA
      s16x8 aq = *(const s16x8*)(lds + LDS_QS + swz512(p0 + li, (h * 32 + g * 8) * 2));
      f32x4 sim[4];
      #pragma unroll
      for (int qb = 0; qb < 4; ++qb) {
        s16x8 bk = *(const s16x8*)(lds + LDS_KS + swz512(qb * 16 + li, (h * 32 + g * 8) * 2));
        sim[qb] = mfma16(aq, bk, (f32x4){0.f, 0.f, 0.f, 0.f});
      }

      // + rel_pos, shift mask
      const float* rps = (const float*)(lds + LDS_RP) + h * 225;
      #pragma unroll
      for (int qb = 0; qb < 4; ++qb)
        #pragma unroll
        for (int r = 0; r < 4; ++r) {
          int p = p0 + g * 4 + r, q = qb * 16 + li;
          int pi = p >> 3, pj = p & 7, qi = q >> 3, qj = q & 7;
          float rel = rps[(pi - qi + 7) * 15 + (pj - qj + 7)];
          bool mk = (mrow && ((pi < 4) != (qi < 4))) || (mcol && ((pj < 4) != (qj < 4)));
          sim[qb][r] = mk ? -1e30f : (sim[qb][r] + rel);
        }

      // row softmax (row lives across 16 lanes x 4 tiles), store probs bf16
      #pragma unroll
      for (int r = 0; r < 4; ++r) {
        float mv = fmaxf(fmaxf(sim[0][r], sim[1][r]), fmaxf(sim[2][r], sim[3][r]));
        mv = fmaxf(mv, __shfl_xor(mv, 1));
        mv = fmaxf(mv, __shfl_xor(mv, 2));
        mv = fmaxf(mv, __shfl_xor(mv, 4));
        mv = fmaxf(mv, __shfl_xor(mv, 8));
        float s = 0.f;
        #pragma unroll
        for (int qb = 0; qb < 4; ++qb) {
          sim[qb][r] = __expf(sim[qb][r] - mv);
          s += sim[qb][r];
        }
        s += __shfl_xor(s, 1);
        s += __shfl_xor(s, 2);
        s += __shfl_xor(s, 4);
        s += __shfl_xor(s, 8);
        const float rinv = 1.f / s;
        const int prow = p0 + g * 4 + r;
        #pragma unroll
        for (int qb = 0; qb < 4; ++qb)
          *(short*)(lds + LDS_PR + hsel * 8192 + swz128(prow, (qb * 16 + li) * 2)) =
              f2bf(sim[qb][r] * rinv);
      }
      asm volatile("s_waitcnt lgkmcnt(0)" ::: "memory");

      // PV: out[p][d] = probs @ V  (B from vT), K=64 -> 2 steps
      f32x4 o[2];
      o[0] = (f32x4){0.f, 0.f, 0.f, 0.f};
      o[1] = (f32x4){0.f, 0.f, 0.f, 0.f};
      #pragma unroll
      for (int ks2 = 0; ks2 < 2; ++ks2) {
        s16x8 ap = *(const s16x8*)(lds + LDS_PR + hsel * 8192
                                   + swz128(p0 + li, (ks2 * 32 + g * 8) * 2));
        #pragma unroll
        for (int dt = 0; dt < 2; ++dt) {
          s16x8 bv = *(const s16x8*)(lds + LDS_VT
                                     + swz128(h * 32 + dt * 16 + li, (ks2 * 32 + g * 8) * 2));
          o[dt] = mfma16(ap, bv, o[dt]);
        }
      }
      // attn split store: hi -> QS (cells this wave already consumed), lo -> XS (dead)
      #pragma unroll
      for (int dt = 0; dt < 2; ++dt)
        #pragma unroll
        for (int r = 0; r < 4; ++r) {
          const float val = o[dt][r];
          const short hi = f2bf(val);
          const short lo = f2bf(val - bf2f(hi));
          const int row = p0 + g * 4 + r;
          const int colB = (h * 32 + dt * 16 + li) * 2;
          *(short*)(lds + LDS_QS + swz512(row, colB)) = hi;
          *(short*)(lds + LDS_XS + swz512(row, colB)) = lo;
        }
    }
  }
  __syncthreads();

  // ---- Phase 3: out-proj, 3-term split-bf16 (Ahi*Bhi + Alo*Bhi + Ahi*Blo) ----
  {
    f32x4 acc2[2][4];
    #pragma unroll
    for (int c = 0; c < 2; ++c)
      #pragma unroll
      for (int rb = 0; rb < 4; ++rb)
        acc2[c][rb] = (f32x4){0.f, 0.f, 0.f, 0.f};

    s16x8 bhc[2], blc[2], bhn[2], bln[2];
    #pragma unroll
    for (int c = 0; c < 2; ++c) {
      const size_t base = (size_t)((w * 2 + c) * 16 + li) * 256 + g * 8;
      bhc[c] = *(const s16x8*)(woutTh + base);
      blc[c] = *(const s16x8*)(woutTl + base);
    }

    #pragma unroll
    for (int kk = 0; kk < 8; ++kk) {
      s16x8 ah[4], al[4];
      #pragma unroll
      for (int rb = 0; rb < 4; ++rb) {
        const int off = swz512(rb * 16 + li, (kk * 32 + g * 8) * 2);
        ah[rb] = *(const s16x8*)(lds + LDS_QS + off);
        al[rb] = *(const s16x8*)(lds + LDS_XS + off);
      }
      if (kk < 7) {
        #pragma unroll
        for (int c = 0; c < 2; ++c) {
          const size_t base = (size_t)((w * 2 + c) * 16 + li) * 256 + (kk + 1) * 32 + g * 8;
          bhn[c] = *(const s16x8*)(woutTh + base);
          bln[c] = *(const s16x8*)(woutTl + base);
        }
      }
      #pragma unroll
      for (int c = 0; c < 2; ++c)
        #pragma unroll
        for (int rb = 0; rb < 4; ++rb) {
          acc2[c][rb] = mfma16(ah[rb], bhc[c], acc2[c][rb]);
          acc2[c][rb] = mfma16(al[rb], bhc[c], acc2[c][rb]);
          acc2[c][rb] = mfma16(ah[rb], blc[c], acc2[c][rb]);
        }
      if (kk < 7) {
        #pragma unroll
        for (int c = 0; c < 2; ++c) { bhc[c] = bhn[c]; blc[c] = bln[c]; }
      }
    }

    #pragma unroll
    for (int c = 0; c < 2; ++c) {
      const int n = (w * 2 + c) * 16 + li;
      const float bo = bout[n];
      #pragma unroll
      for (int rb = 0; rb < 4; ++rb)
        #pragma unroll
        for (int r = 0; r < 4; ++r) {
          int m = rb * 16 + g * 4 + r;
          int pi = m >> 3, pj = m & 7;
          int dr = (wh * 8 + pi + 4) & 255;
          int dc = (wwi * 8 + pj + 4) & 255;
          out[(((size_t)b * 256 + dr) * 256 + dc) * 256 + n] = acc2[c][rb][r] + bo;
        }
    }
  }
}

extern "C" void kernel_launch(void* const* d_in, const int* in_sizes, int n_in,
                              void* d_out, int out_size, void* d_ws, size_t ws_size,
                              hipStream_t stream) {
  (void)in_sizes; (void)n_in; (void)out_size; (void)ws_size;
  const float* x    = (const float*)d_in[0];
  const float* Wqkv = (const float*)d_in[1];
  const float* bqkv = (const float*)d_in[2];
  const float* relp = (const float*)d_in[3];
  const float* Wout = (const float*)d_in[4];
  const float* bout = (const float*)d_in[5];
  float* out = (float*)d_out;

  short* wqkvT  = (short*)d_ws;                 // 768*256 bf16
  short* woutTh = wqkvT + 768 * 256;            // 256*256 bf16
  short* woutTl = woutTh + 256 * 256;           // 256*256 bf16

  hipLaunchKernelGGL(prep_w, dim3(1024), dim3(256), 0, stream,
                     Wqkv, Wout, wqkvT, woutTh, woutTl);
  hipLaunchKernelGGL(swin_mfma, dim3(4096), dim3(512), 0, stream,
                     x, bqkv, relp, bout, wqkvT, woutTh, woutTl, out);
}

// Round 5
// 477.410 us; speedup vs baseline: 10.5248x; 1.3432x over previous
//
#include <hip/hip_runtime.h>

typedef __attribute__((ext_vector_type(4))) float f32x4;
typedef __attribute__((ext_vector_type(8))) short s16x8;
typedef __attribute__((ext_vector_type(4))) short s16x4;
typedef __attribute__((ext_vector_type(8))) __bf16 bf16v8;

// LDS layout (bytes)
#define LDS_XS 0        // 32768: x window bf16 [64 tok][256 ch] swz512; phase2+: attn_lo
#define LDS_QS 32768    // 32768: Q bf16 [64 tok][256 col] (pre-scaled) swz512; phase2+: attn_hi
#define LDS_KS 65536    // 32768: K bf16 [64 tok][256 col], swz512
#define LDS_VT 98304    // 32768: V^T bf16 [256 col][64 tok], swz128
#define LDS_PR 131072   // 16384: P' bf16 [2 hsel][64 p][64 q], swz128
#define LDS_TOT 147456

__device__ __forceinline__ f32x4 mfma16(s16x8 a, s16x8 b, f32x4 c) {
  return __builtin_amdgcn_mfma_f32_16x16x32_bf16(
      __builtin_bit_cast(bf16v8, a), __builtin_bit_cast(bf16v8, b), c, 0, 0, 0);
}

__device__ __forceinline__ short f2bf(float f) {
  unsigned u = __float_as_uint(f);
  u += 0x7fffu + ((u >> 16) & 1u);
  return (short)(u >> 16);
}
__device__ __forceinline__ float bf2f(short h) {
  return __uint_as_float(((unsigned)(unsigned short)h) << 16);
}

__device__ __forceinline__ int swz512(int row, int colByte) {
  return row * 512 + (colByte ^ ((row & 7) << 4));
}
__device__ __forceinline__ int swz128(int row, int colByte) {
  return row * 128 + (colByte ^ ((row & 7) << 4));
}

// Prep: WqkvT[n][k] bf16 (768x256); WoutT hi/lo [n][k] bf16 (256x256);
// RELT[var][h][qt][strip][lane][r] f32 = masked rel_pos in simT C-frag order.
__global__ void prep_w(const float* __restrict__ Wqkv, const float* __restrict__ Wout,
                       const float* __restrict__ relp,
                       short* __restrict__ wqkvT, short* __restrict__ woutTh,
                       short* __restrict__ woutTl, float* __restrict__ relt) {
  int t = blockIdx.x * 256 + threadIdx.x;
  if (t < 768 * 256) {
    int n = t >> 8, k = t & 255;
    wqkvT[t] = f2bf(Wqkv[k * 768 + n]);
  } else if (t < 768 * 256 + 256 * 256) {
    int t2 = t - 768 * 256;
    int n = t2 >> 8, k = t2 & 255;
    float wv = Wout[k * 256 + n];
    short hi = f2bf(wv);
    woutTh[t2] = hi;
    woutTl[t2] = f2bf(wv - bf2f(hi));
  } else {
    int u = t - 768 * 256 - 256 * 256;   // 0 .. 131071
    int r = u & 3, l = (u >> 2) & 63, strip = (u >> 8) & 3;
    int qt = (u >> 10) & 3, h = (u >> 12) & 7, var = (u >> 15) & 3;
    int p = strip * 16 + (l & 15);
    int q = qt * 16 + ((l >> 4) << 2) + r;
    int pi = p >> 3, pj = p & 7, qi = q >> 3, qj = q & 7;
    bool mrow = (var >> 1) & 1, mcol = var & 1;
    bool mk = (mrow && ((pi < 4) != (qi < 4))) || (mcol && ((pj < 4) != (qj < 4)));
    relt[u] = mk ? -1e30f : relp[h * 225 + (pi - qi + 7) * 15 + (pj - qj + 7)];
  }
}

// One block per (batch, window). 512 threads = 8 waves.
__global__ __launch_bounds__(512, 2) void swin_mfma(
    const float* __restrict__ x, const float* __restrict__ bqkv,
    const float* __restrict__ bout,
    const short* __restrict__ wqkvT, const short* __restrict__ woutTh,
    const short* __restrict__ woutTl, const float* __restrict__ relt,
    float* __restrict__ out)
{
  __shared__ __align__(16) char lds[LDS_TOT];

  const int tx = threadIdx.x;
  const int w  = tx >> 6;         // wave 0..7
  const int l  = tx & 63;         // lane
  const int g  = l >> 4;          // k-group 0..3
  const int li = l & 15;          // row/col within fragment

  const int b   = blockIdx.x >> 10;
  const int wdw = blockIdx.x & 1023;
  const int wh  = wdw >> 5, wwi = wdw & 31;

  // ---- Phase 0: stage x window (rolled -4) as bf16 into LDS ----
  for (int i = 0; i < 8; ++i) {
    int idx = tx + i * 512;       // 0..4095
    int p = idx >> 6, c4 = idx & 63;
    int pi = p >> 3, pj = p & 7;
    int sr = (wh * 8 + pi + 4) & 255;
    int sc = (wwi * 8 + pj + 4) & 255;
    f32x4 v = *(const f32x4*)(x + ((((size_t)b * 256 + sr) * 256 + sc) * 256 + c4 * 4));
    s16x4 h4;
    h4.x = f2bf(v.x); h4.y = f2bf(v.y); h4.z = f2bf(v.z); h4.w = f2bf(v.w);
    *(s16x4*)(lds + LDS_XS + swz512(p, c4 * 8)) = h4;
  }
  __syncthreads();

  // ---- Phase 1: QKV GEMM. Wave w: Q/K col-blocks w*4..w*4+3 (swapped operands,
  //      C = [outcol][token]); V col-blocks w*2, w*2+1 (normal, C = [token][vcol]). ----
  {
    f32x4 acc[6][4];
    #pragma unroll
    for (int j = 0; j < 6; ++j)
      #pragma unroll
      for (int rb = 0; rb < 4; ++rb)
        acc[j][rb] = (f32x4){0.f, 0.f, 0.f, 0.f};

    // wqkvT row (= out column) per j
    int ocol[6];
    #pragma unroll
    for (int j = 0; j < 4; ++j) ocol[j] = (w * 4 + j) * 16 + li;
    #pragma unroll
    for (int j = 4; j < 6; ++j) ocol[j] = 512 + (w * 2 + (j - 4)) * 16 + li;

    s16x8 bcur[6], bnext[6];
    #pragma unroll
    for (int j = 0; j < 6; ++j)
      bcur[j] = *(const s16x8*)(wqkvT + (size_t)ocol[j] * 256 + g * 8);

    #pragma unroll
    for (int kk = 0; kk < 8; ++kk) {
      s16x8 a[4];
      #pragma unroll
      for (int rb = 0; rb < 4; ++rb)
        a[rb] = *(const s16x8*)(lds + LDS_XS + swz512(rb * 16 + li, kk * 64 + g * 16));
      if (kk < 7) {
        #pragma unroll
        for (int j = 0; j < 6; ++j)
          bnext[j] = *(const s16x8*)(wqkvT + (size_t)ocol[j] * 256 + (kk + 1) * 32 + g * 8);
      }
      #pragma unroll
      for (int j = 0; j < 4; ++j)          // Q,K: swapped -> C[outcol][token]
        #pragma unroll
        for (int rb = 0; rb < 4; ++rb)
          acc[j][rb] = mfma16(bcur[j], a[rb], acc[j][rb]);
      #pragma unroll
      for (int j = 4; j < 6; ++j)          // V: normal -> C[token][vcol]
        #pragma unroll
        for (int rb = 0; rb < 4; ++rb)
          acc[j][rb] = mfma16(a[rb], bcur[j], acc[j][rb]);
      if (kk < 7) {
        #pragma unroll
        for (int j = 0; j < 6; ++j) bcur[j] = bnext[j];
      }
    }

    // Packed b64 stores.
    #pragma unroll
    for (int j = 0; j < 4; ++j) {          // Q or K: row=token(rb*16+li), 4 consec cols
      const int cb = w * 4 + j;
      if (cb < 16) {                       // Q (pre-scaled)
        f32x4 bq = *(const f32x4*)(bqkv + cb * 16 + g * 4);
        #pragma unroll
        for (int rb = 0; rb < 4; ++rb) {
          s16x4 pk;
          pk.x = f2bf((acc[j][rb][0] + bq[0]) * 0.17677669529663687f);
          pk.y = f2bf((acc[j][rb][1] + bq[1]) * 0.17677669529663687f);
          pk.z = f2bf((acc[j][rb][2] + bq[2]) * 0.17677669529663687f);
          pk.w = f2bf((acc[j][rb][3] + bq[3]) * 0.17677669529663687f);
          *(s16x4*)(lds + LDS_QS + swz512(rb * 16 + li, cb * 32 + g * 8)) = pk;
        }
      } else {                             // K
        f32x4 bk = *(const f32x4*)(bqkv + 256 + (cb - 16) * 16 + g * 4);
        #pragma unroll
        for (int rb = 0; rb < 4; ++rb) {
          s16x4 pk;
          pk.x = f2bf(acc[j][rb][0] + bk[0]);
          pk.y = f2bf(acc[j][rb][1] + bk[1]);
          pk.z = f2bf(acc[j][rb][2] + bk[2]);
          pk.w = f2bf(acc[j][rb][3] + bk[3]);
          *(s16x4*)(lds + LDS_KS + swz512(rb * 16 + li, (cb - 16) * 32 + g * 8)) = pk;
        }
      }
    }
    #pragma unroll
    for (int j = 4; j < 6; ++j) {          // V -> VT[d][token]: row=d(li), 4 consec tokens
      const int d = (w * 2 + (j - 4)) * 16 + li;
      const float bv = bqkv[512 + d];
      #pragma unroll
      for (int rb = 0; rb < 4; ++rb) {
        s16x4 pk;
        pk.x = f2bf(acc[j][rb][0] + bv);
        pk.y = f2bf(acc[j][rb][1] + bv);
        pk.z = f2bf(acc[j][rb][2] + bv);
        pk.w = f2bf(acc[j][rb][3] + bv);
        *(s16x4*)(lds + LDS_VT + swz128(d, rb * 32 + g * 8)) = pk;
      }
    }
  }
  __syncthreads();

  // ---- Phase 2: attention. Wave w: heads hp*2+(w>>2), rows (w&3)*16..+15.
  //      simT = mfma(K,Q,RELT); P'=exp(simT); sums=mfma(ones,P'); attnT=mfma(V,P'). ----
  {
    const int rvar = ((wh == 31) ? 2 : 0) | ((wwi == 31) ? 1 : 0);
    const int hsel = w >> 2, strip = w & 3, p0 = strip * 16;
    const short ONE = (short)0x3F80;
    const s16x8 ones = {ONE, ONE, ONE, ONE, ONE, ONE, ONE, ONE};

    #pragma unroll
    for (int hp = 0; hp < 4; ++hp) {
      const int h = hp * 2 + hsel;

      // masked rel_pos C-init (coalesced f32x4 from L2 table)
      f32x4 rc[4];
      #pragma unroll
      for (int qt = 0; qt < 4; ++qt)
        rc[qt] = *(const f32x4*)(relt + ((((rvar * 8 + h) * 4 + qt) * 4 + strip) * 64 + l) * 4);

      // simT[qt] (m=q, n=p)
      s16x8 qf = *(const s16x8*)(lds + LDS_QS + swz512(p0 + li, h * 64 + g * 16));
      f32x4 simT[4];
      #pragma unroll
      for (int qt = 0; qt < 4; ++qt) {
        s16x8 kf = *(const s16x8*)(lds + LDS_KS + swz512(qt * 16 + li, h * 64 + g * 16));
        simT[qt] = mfma16(kf, qf, rc[qt]);
      }

      // P' = exp(simT) (no-max softmax; masked = exp(-1e30) = 0), packed b64 store
      #pragma unroll
      for (int qt = 0; qt < 4; ++qt) {
        s16x4 pk;
        pk.x = f2bf(__expf(simT[qt][0]));
        pk.y = f2bf(__expf(simT[qt][1]));
        pk.z = f2bf(__expf(simT[qt][2]));
        pk.w = f2bf(__expf(simT[qt][3]));
        *(s16x4*)(lds + LDS_PR + hsel * 8192 + swz128(p0 + li, qt * 32 + g * 8)) = pk;
      }

      // P' fragments (B operand for both sums and attnT)
      s16x8 pf[2];
      #pragma unroll
      for (int ks = 0; ks < 2; ++ks)
        pf[ks] = *(const s16x8*)(lds + LDS_PR + hsel * 8192 + swz128(p0 + li, ks * 64 + g * 16));

      f32x4 s = (f32x4){0.f, 0.f, 0.f, 0.f};
      f32x4 at0 = (f32x4){0.f, 0.f, 0.f, 0.f};
      f32x4 at1 = (f32x4){0.f, 0.f, 0.f, 0.f};
      #pragma unroll
      for (int ks = 0; ks < 2; ++ks) {
        s = mfma16(ones, pf[ks], s);
        s16x8 vf0 = *(const s16x8*)(lds + LDS_VT + swz128(h * 32 + li, ks * 64 + g * 16));
        s16x8 vf1 = *(const s16x8*)(lds + LDS_VT + swz128(h * 32 + 16 + li, ks * 64 + g * 16));
        at0 = mfma16(vf0, pf[ks], at0);
        at1 = mfma16(vf1, pf[ks], at1);
      }
      const float rinv = 1.0f / s[0];

      // attn hi/lo packed stores: row = p (p0+li), 4 consecutive channels
      #pragma unroll
      for (int dt = 0; dt < 2; ++dt) {
        const f32x4 at = dt ? at1 : at0;
        s16x4 hi4, lo4;
        #pragma unroll
        for (int r = 0; r < 4; ++r) {
          float v = at[r] * rinv;
          short hi = f2bf(v);
          hi4[r] = hi;
          lo4[r] = f2bf(v - bf2f(hi));
        }
        const int cByte = h * 64 + dt * 32 + g * 8;
        *(s16x4*)(lds + LDS_QS + swz512(p0 + li, cByte)) = hi4;
        *(s16x4*)(lds + LDS_XS + swz512(p0 + li, cByte)) = lo4;
      }
    }
  }
  __syncthreads();

  // ---- Phase 3: out-proj, 3-term split-bf16 (Ahi*Bhi + Alo*Bhi + Ahi*Blo) ----
  {
    f32x4 acc2[2][4];
    #pragma unroll
    for (int c = 0; c < 2; ++c)
      #pragma unroll
      for (int rb = 0; rb < 4; ++rb)
        acc2[c][rb] = (f32x4){0.f, 0.f, 0.f, 0.f};

    s16x8 bhc[2], blc[2], bhn[2], bln[2];
    #pragma unroll
    for (int c = 0; c < 2; ++c) {
      const size_t base = (size_t)((w * 2 + c) * 16 + li) * 256 + g * 8;
      bhc[c] = *(const s16x8*)(woutTh + base);
      blc[c] = *(const s16x8*)(woutTl + base);
    }

    #pragma unroll
    for (int kk = 0; kk < 8; ++kk) {
      s16x8 ah[4], al[4];
      #pragma unroll
      for (int rb = 0; rb < 4; ++rb) {
        const int off = swz512(rb * 16 + li, kk * 64 + g * 16);
        ah[rb] = *(const s16x8*)(lds + LDS_QS + off);
        al[rb] = *(const s16x8*)(lds + LDS_XS + off);
      }
      if (kk < 7) {
        #pragma unroll
        for (int c = 0; c < 2; ++c) {
          const size_t base = (size_t)((w * 2 + c) * 16 + li) * 256 + (kk + 1) * 32 + g * 8;
          bhn[c] = *(const s16x8*)(woutTh + base);
          bln[c] = *(const s16x8*)(woutTl + base);
        }
      }
      #pragma unroll
      for (int c = 0; c < 2; ++c)
        #pragma unroll
        for (int rb = 0; rb < 4; ++rb) {
          acc2[c][rb] = mfma16(ah[rb], bhc[c], acc2[c][rb]);
          acc2[c][rb] = mfma16(al[rb], bhc[c], acc2[c][rb]);
          acc2[c][rb] = mfma16(ah[rb], blc[c], acc2[c][rb]);
        }
      if (kk < 7) {
        #pragma unroll
        for (int c = 0; c < 2; ++c) { bhc[c] = bhn[c]; blc[c] = bln[c]; }
      }
    }

    #pragma unroll
    for (int c = 0; c < 2; ++c) {
      const int n = (w * 2 + c) * 16 + li;
      const float bo = bout[n];
      #pragma unroll
      for (int rb = 0; rb < 4; ++rb)
        #pragma unroll
        for (int r = 0; r < 4; ++r) {
          int m = rb * 16 + g * 4 + r;
          int pi = m >> 3, pj = m & 7;
          int dr = (wh * 8 + pi + 4) & 255;
          int dc = (wwi * 8 + pj + 4) & 255;
          out[(((size_t)b * 256 + dr) * 256 + dc) * 256 + n] = acc2[c][rb][r] + bo;
        }
    }
  }
}

extern "C" void kernel_launch(void* const* d_in, const int* in_sizes, int n_in,
                              void* d_out, int out_size, void* d_ws, size_t ws_size,
                              hipStream_t stream) {
  (void)in_sizes; (void)n_in; (void)out_size; (void)ws_size;
  const float* x    = (const float*)d_in[0];
  const float* Wqkv = (const float*)d_in[1];
  const float* bqkv = (const float*)d_in[2];
  const float* relp = (const float*)d_in[3];
  const float* Wout = (const float*)d_in[4];
  const float* bout = (const float*)d_in[5];
  float* out = (float*)d_out;

  short* wqkvT  = (short*)d_ws;                 // 768*256 bf16
  short* woutTh = wqkvT + 768 * 256;            // 256*256 bf16
  short* woutTl = woutTh + 256 * 256;           // 256*256 bf16
  float* relt   = (float*)(woutTl + 256 * 256); // 4*8*4*4*256 f32 = 512KB

  // 768*256 + 256*256 + 131072 elements -> 1536 blocks of 256
  hipLaunchKernelGGL(prep_w, dim3(1536), dim3(256), 0, stream,
                     Wqkv, Wout, relp, wqkvT, woutTh, woutTl, relt);
  hipLaunchKernelGGL(swin_mfma, dim3(4096), dim3(512), 0, stream,
                     x, bqkv, bout, wqkvT, woutTh, woutTl, relt, out);
}